// Round 1
// baseline (143.941 us; speedup 1.0000x reference)
//
#include <hip/hip_runtime.h>

// Problem constants
#define NN    32
#define CC    49
#define HWSZ  81
#define MSZ   24
#define KSZ   7
#define PADSZ 3
#define XR    84            // padded row stride in floats (16B-aligned rows, 21 float4)
#define XROWS 55            // 3 zero rows + 49 data rows + 3 zero rows
#define NHW   (NN*HWSZ)     // 2592

// Kernel 1: one block per (n, o). Computes mask rows for its 49 j's,
// fk[c][dd] with leaky factor applied, and atomically accumulates the
// partial out[c][hw] into d_out (pre-zeroed by memset).
__global__ __launch_bounds__(256) void fuse_k1(
    const float* __restrict__ x, const float* __restrict__ cw,
    const float* __restrict__ cb, float* __restrict__ acc)
{
    __shared__ float xs[XROWS * XR];   // 4620 floats, zero-padded halo + cols
    __shared__ float msk[CC * XR];     // 4116 floats, softmax rows (pad cols = 0)
    __shared__ float g[CC * CC];       // 2401 floats, f(fk)[c][dd]

    const int o = blockIdx.x;          // 0..23
    const int n = blockIdx.y;          // 0..31
    const int t = threadIdx.x;
    const int lane = t & 63;
    const int wv = t >> 6;

    // ---- stage x[n] into LDS with zero padding (rows shifted +3 for conv halo)
    const float* xn = x + (size_t)n * CC * HWSZ;
    for (int i = t; i < XROWS * XR; i += 256) {
        int r = i / XR, col = i - r * XR;
        float v = 0.f;
        if (r >= PADSZ && r < PADSZ + CC && col < HWSZ)
            v = xn[(r - PADSZ) * HWSZ + col];
        xs[i] = v;
    }
    float wk[KSZ];
    #pragma unroll
    for (int k = 0; k < KSZ; ++k) wk[k] = cw[o * KSZ + k];
    const float bias = cb[o];
    __syncthreads();

    // ---- conv over depth + softmax over 81 spatial cols; one row per wave-iter
    for (int dd = wv; dd < CC; dd += 4) {
        const int c0 = lane, c1 = lane + 64;
        float m0 = bias, m1 = -1e30f;
        #pragma unroll
        for (int k = 0; k < KSZ; ++k) m0 += wk[k] * xs[(dd + k) * XR + c0];
        if (c1 < HWSZ) {
            float s = bias;
            #pragma unroll
            for (int k = 0; k < KSZ; ++k) s += wk[k] * xs[(dd + k) * XR + c1];
            m1 = s;
        }
        float mx = fmaxf(m0, m1);
        #pragma unroll
        for (int off = 32; off; off >>= 1) mx = fmaxf(mx, __shfl_xor(mx, off, 64));
        float e0 = __expf(m0 - mx);
        float e1 = (c1 < HWSZ) ? __expf(m1 - mx) : 0.f;
        float sm = e0 + e1;
        #pragma unroll
        for (int off = 32; off; off >>= 1) sm += __shfl_xor(sm, off, 64);
        float inv = 1.f / sm;
        msk[dd * XR + c0] = e0 * inv;
        if (c1 < XR) msk[dd * XR + c1] = (c1 < HWSZ) ? e1 * inv : 0.f; // zero pad cols
    }
    __syncthreads();

    // ---- fk[c][dd] = mask_row(dd) . x_row(c), leaky factor applied.
    // 4 channels per work item, float4 LDS loads (rows are 16B aligned,
    // pad cols are zero so summing cols 81..83 is harmless).
    for (int it = t; it < CC * 13; it += 256) {
        int dd = it / 13;
        int cg = (it - dd * 13) * 4;
        const float4* m4 = (const float4*)(msk + dd * XR);
        const float4* x4 = (const float4*)(xs + (cg + PADSZ) * XR);
        float4 a0 = {0,0,0,0}, a1 = {0,0,0,0}, a2 = {0,0,0,0}, a3 = {0,0,0,0};
        #pragma unroll 7
        for (int q = 0; q < 21; ++q) {
            float4 m  = m4[q];
            float4 r0 = x4[q];
            float4 r1 = x4[21 + q];
            float4 r2 = x4[42 + q];
            float4 r3 = x4[63 + q];
            a0.x += m.x * r0.x; a0.y += m.y * r0.y; a0.z += m.z * r0.z; a0.w += m.w * r0.w;
            a1.x += m.x * r1.x; a1.y += m.y * r1.y; a1.z += m.z * r1.z; a1.w += m.w * r1.w;
            a2.x += m.x * r2.x; a2.y += m.y * r2.y; a2.z += m.z * r2.z; a2.w += m.w * r2.w;
            a3.x += m.x * r3.x; a3.y += m.y * r3.y; a3.z += m.z * r3.z; a3.w += m.w * r3.w;
        }
        float s0 = a0.x + a0.y + a0.z + a0.w;
        float s1 = a1.x + a1.y + a1.z + a1.w;
        float s2 = a2.x + a2.y + a2.z + a2.w;
        float s3 = a3.x + a3.y + a3.z + a3.w;
        g[(cg + 0) * CC + dd] = (s0 >= 0.f) ? s0 : 0.01f * s0;
        if (cg + 1 < CC) g[(cg + 1) * CC + dd] = (s1 >= 0.f) ? s1 : 0.01f * s1;
        if (cg + 2 < CC) g[(cg + 2) * CC + dd] = (s2 >= 0.f) ? s2 : 0.01f * s2;
        if (cg + 3 < CC) g[(cg + 3) * CC + dd] = (s3 >= 0.f) ? s3 : 0.01f * s3;
    }
    __syncthreads();

    // ---- out_partial[c][hw] = sum_dd g[c][dd] * msk[dd][hw]; atomic accumulate
    float* accn = acc + (size_t)n * CC * HWSZ;
    for (int it = t; it < CC * 21; it += 256) {
        int c = it / 21;
        int hg = it - c * 21;
        const float* gr = g + c * CC;
        const float4* m4 = (const float4*)msk;
        float4 s = {0,0,0,0};
        #pragma unroll 7
        for (int dd = 0; dd < CC; ++dd) {
            float gv = gr[dd];
            float4 m = m4[dd * 21 + hg];
            s.x += gv * m.x; s.y += gv * m.y; s.z += gv * m.z; s.w += gv * m.w;
        }
        int hw = hg * 4;
        float* dst = accn + c * HWSZ + hw;
        atomicAdd(dst, s.x);
        if (hw + 1 < HWSZ) atomicAdd(dst + 1, s.y);
        if (hw + 2 < HWSZ) atomicAdd(dst + 2, s.z);
        if (hw + 3 < HWSZ) atomicAdd(dst + 3, s.w);
    }
}

// Kernel 2: one block per channel c. Residual add + batch-norm over (N,H,W),
// in-place on d_out (block owns the whole channel; reads complete before the
// reduction barrier, writes after).
__global__ __launch_bounds__(256) void fuse_k2(
    float* __restrict__ out, const float* __restrict__ x,
    const float* __restrict__ gamma, const float* __restrict__ beta)
{
    const int c = blockIdx.x;
    const int t = threadIdx.x;
    float vals[11];
    float sum = 0.f, sq = 0.f;
    int cnt = 0;
    for (int i = t; i < NHW; i += 256) {
        int n = i / HWSZ;
        int hw = i - n * HWSZ;
        int idx = (n * CC + c) * HWSZ + hw;
        float v = out[idx] + x[idx];
        vals[cnt++] = v;
        sum += v; sq += v * v;
    }
    #pragma unroll
    for (int off = 32; off; off >>= 1) {
        sum += __shfl_xor(sum, off, 64);
        sq  += __shfl_xor(sq, off, 64);
    }
    __shared__ float rs[4], rq[4];
    const int lane = t & 63, wv = t >> 6;
    if (lane == 0) { rs[wv] = sum; rq[wv] = sq; }
    __syncthreads();
    float ts = rs[0] + rs[1] + rs[2] + rs[3];
    float tq = rq[0] + rq[1] + rq[2] + rq[3];
    const float invD = 1.f / (float)NHW;
    float mean = ts * invD;
    float var  = tq * invD - mean * mean;
    float scal = rsqrtf(var + 1e-5f) * gamma[c];
    float shft = beta[c] - mean * scal;
    cnt = 0;
    for (int i = t; i < NHW; i += 256) {
        int n = i / HWSZ;
        int hw = i - n * HWSZ;
        int idx = (n * CC + c) * HWSZ + hw;
        out[idx] = vals[cnt++] * scal + shft;
    }
}

extern "C" void kernel_launch(void* const* d_in, const int* in_sizes, int n_in,
                              void* d_out, int out_size, void* d_ws, size_t ws_size,
                              hipStream_t stream) {
    const float* x     = (const float*)d_in[0];
    const float* cw    = (const float*)d_in[1];
    const float* cb    = (const float*)d_in[2];
    const float* gamma = (const float*)d_in[3];
    const float* beta  = (const float*)d_in[4];
    float* out = (float*)d_out;

    // d_out doubles as the fp32 accumulator for the partial sums over o.
    hipMemsetAsync(out, 0, (size_t)NN * CC * HWSZ * sizeof(float), stream);
    fuse_k1<<<dim3(MSZ, NN), 256, 0, stream>>>(x, cw, cb, out);
    fuse_k2<<<CC, 256, 0, stream>>>(out, x, gamma, beta);
}

// Round 2
// 106.175 us; speedup vs baseline: 1.3557x; 1.3557x over previous
//
#include <hip/hip_runtime.h>
#include <hip/hip_bf16.h>

// Problem constants
#define NN    32
#define CC    49
#define HWSZ  81
#define MSZ   24
#define KSZ   7
#define PADSZ 3
#define NHW   (NN*HWSZ)     // 2592

// LDS strides (in shorts / bf16 elements). All row strides * 2B are multiples
// of 16B (b128-aligned fragment loads) and chosen to stagger bank starts.
#define XSB_S  104   // xsb[64][104]  : x[n] as bf16, rows c (0..48 data, 49..63 zero)
#define MSK_S  104   // msk[64][104]  : mask rows dd, cols hw (81..95 zero, rows 49..63 zero)
#define MSKT_S 88    // mskT[96][88]  : mask transposed, rows hw, cols dd
#define G_S    80    // gm[64][80]    : leaky(fk)[c][dd]

typedef __attribute__((ext_vector_type(8))) short short8;
typedef __attribute__((ext_vector_type(4))) short short4v;
typedef __attribute__((ext_vector_type(4))) float f32x4;

__device__ __forceinline__ short f2b(float v) {
    unsigned u = __float_as_uint(v);
    u += 0x7fffu + ((u >> 16) & 1u);      // round-to-nearest-even to bf16
    return (short)(u >> 16);
}

// Kernel 1: one block (256 thr = 4 waves) per (n, o).
//   phase 1: conv(K=7 over channel) + softmax(81) from global fp32 x -> msk/mskT (bf16 LDS)
//   phase 2: MFMA  fkT[dd][c] = msk(64x96) . xsb^T  -> leaky -> gm[c][dd] (bf16 LDS)
//   phase 3: MFMA  out[c][hw] = gm(64x64) . mskT^T(64x96) -> fp32 atomicAdd into d_out
__global__ __launch_bounds__(256) void fuse_k1(
    const float* __restrict__ x, const float* __restrict__ cw,
    const float* __restrict__ cb, float* __restrict__ acc)
{
    __shared__ short xsb [64 * XSB_S];    // 13312 B
    __shared__ short msk [64 * MSK_S];    // 13312 B
    __shared__ short mskT[96 * MSKT_S];   // 16896 B
    __shared__ short gm  [64 * G_S];      // 10240 B  (fully overwritten, no zeroing)

    const int o = blockIdx.x;          // 0..23
    const int n = blockIdx.y;          // 0..31
    const int t = threadIdx.x;
    const int lane = t & 63;
    const int wv = t >> 6;             // 0..3
    const int lr = lane & 15;          // MFMA row/col index
    const int lq = lane >> 4;          // MFMA k-group / reg-group

    // ---- zero-fill the padded LDS operands (float4 = 8 shorts per store)
    {
        f32x4 z = {0.f, 0.f, 0.f, 0.f};
        for (int i = t; i < 832; i += 256) {        // 6656 shorts each
            ((f32x4*)xsb)[i] = z;
            ((f32x4*)msk)[i] = z;
        }
        for (int i = t; i < 1056; i += 256)         // 8448 shorts
            ((f32x4*)mskT)[i] = z;
    }

    const float* xg = x + (size_t)n * CC * HWSZ;
    float wk[KSZ];
    #pragma unroll
    for (int k = 0; k < KSZ; ++k) wk[k] = cw[o * KSZ + k];
    const float bias = cb[o];
    __syncthreads();

    // ---- stage x[n] into xsb (bf16, row-major [c][hw])
    for (int i = t; i < CC * HWSZ; i += 256) {
        int c = i / HWSZ, hw = i - c * HWSZ;
        xsb[c * XSB_S + hw] = f2b(xg[i]);
    }

    // ---- conv over channel dim + softmax over 81 cols; one dd-row per wave-iter.
    // Reads fp32 x from global (L1/L2 resident) to keep softmax full precision.
    for (int dd = wv; dd < CC; dd += 4) {
        const int c0 = lane, c1 = lane + 64;
        float a0 = 0.f, a1 = 0.f;
        #pragma unroll
        for (int k = 0; k < KSZ; ++k) {
            int r = dd + k - PADSZ;
            if (r >= 0 && r < CC) {
                a0 += wk[k] * xg[r * HWSZ + c0];
                if (c1 < HWSZ) a1 += wk[k] * xg[r * HWSZ + c1];
            }
        }
        float m0 = bias + a0;
        float m1 = (c1 < HWSZ) ? bias + a1 : -1e30f;
        float mx = fmaxf(m0, m1);
        #pragma unroll
        for (int off = 32; off; off >>= 1) mx = fmaxf(mx, __shfl_xor(mx, off, 64));
        float e0 = __expf(m0 - mx);
        float e1 = (c1 < HWSZ) ? __expf(m1 - mx) : 0.f;
        float sm = e0 + e1;
        #pragma unroll
        for (int off = 32; off; off >>= 1) sm += __shfl_xor(sm, off, 64);
        float inv = 1.f / sm;
        short b0 = f2b(e0 * inv);
        msk [dd * MSK_S  + c0] = b0;
        mskT[c0 * MSKT_S + dd] = b0;
        if (c1 < HWSZ) {
            short b1 = f2b(e1 * inv);
            msk [dd * MSK_S  + c1] = b1;
            mskT[c1 * MSKT_S + dd] = b1;
        }
    }
    __syncthreads();

    // ---- matmul-2 (MFMA): fkT[dd][c] = sum_hw msk[dd][hw] * xsb[c][hw]
    // M=dd (4 tiles, one per wave), N=c (4 tiles), K=hw (96, 3 steps).
    // A-frag: lane holds msk[mt*16+lr][ks*32+lq*8 + 0..7]  (row-contig, 16B aligned)
    // B-frag: lane holds xsb[nt*16+lr][ks*32+lq*8 + 0..7]
    {
        short8 a2[3];
        #pragma unroll
        for (int ks = 0; ks < 3; ++ks)
            a2[ks] = *(const short8*)&msk[(wv * 16 + lr) * MSK_S + ks * 32 + lq * 8];
        #pragma unroll
        for (int nt = 0; nt < 4; ++nt) {
            f32x4 accv = {0.f, 0.f, 0.f, 0.f};
            #pragma unroll
            for (int ks = 0; ks < 3; ++ks) {
                short8 b = *(const short8*)&xsb[(nt * 16 + lr) * XSB_S + ks * 32 + lq * 8];
                accv = __builtin_amdgcn_mfma_f32_16x16x32_bf16(a2[ks], b, accv, 0, 0, 0);
            }
            // C-layout: lane holds fkT[dd = wv*16 + lq*4 + r][c = nt*16 + lr]
            // leaky, then store transposed into gm[c][dd] (4 consecutive dd -> b64)
            short4v pk;
            #pragma unroll
            for (int r = 0; r < 4; ++r) {
                float v = accv[r];
                v = (v >= 0.f) ? v : 0.01f * v;
                pk[r] = f2b(v);
            }
            *(short4v*)&gm[(nt * 16 + lr) * G_S + wv * 16 + lq * 4] = pk;
        }
    }
    __syncthreads();

    // ---- matmul-1 (MFMA): out[c][hw] = sum_dd gm[c][dd] * mskT[hw][dd]
    // M=c (4 tiles, one per wave), N=hw (6 tiles), K=dd (64, 2 steps).
    {
        float* accn = acc + (size_t)n * CC * HWSZ;
        short8 a1[2];
        #pragma unroll
        for (int ks = 0; ks < 2; ++ks)
            a1[ks] = *(const short8*)&gm[(wv * 16 + lr) * G_S + ks * 32 + lq * 8];
        #pragma unroll
        for (int nt = 0; nt < 6; ++nt) {
            f32x4 accv = {0.f, 0.f, 0.f, 0.f};
            #pragma unroll
            for (int ks = 0; ks < 2; ++ks) {
                short8 b = *(const short8*)&mskT[(nt * 16 + lr) * MSKT_S + ks * 32 + lq * 8];
                accv = __builtin_amdgcn_mfma_f32_16x16x32_bf16(a1[ks], b, accv, 0, 0, 0);
            }
            // C-layout: lane holds out[c = wv*16 + lq*4 + r][hw = nt*16 + lr]
            int hw = nt * 16 + lr;
            if (hw < HWSZ) {
                int cb = wv * 16 + lq * 4;
                #pragma unroll
                for (int r = 0; r < 4; ++r) {
                    int c = cb + r;
                    if (c < CC) atomicAdd(accn + c * HWSZ + hw, accv[r]);
                }
            }
        }
    }
}

// Kernel 2: one block per channel c (512 thr). Residual add + batch-norm over
// (N,H,W), in-place on d_out.
__global__ __launch_bounds__(512) void fuse_k2(
    float* __restrict__ out, const float* __restrict__ x,
    const float* __restrict__ gamma, const float* __restrict__ beta)
{
    const int c = blockIdx.x;
    const int t = threadIdx.x;
    float vals[6];
    float sum = 0.f, sq = 0.f;
    int cnt = 0;
    for (int i = t; i < NHW; i += 512) {
        int n = i / HWSZ;
        int hw = i - n * HWSZ;
        int idx = (n * CC + c) * HWSZ + hw;
        float v = out[idx] + x[idx];
        vals[cnt++] = v;
        sum += v; sq += v * v;
    }
    #pragma unroll
    for (int off = 32; off; off >>= 1) {
        sum += __shfl_xor(sum, off, 64);
        sq  += __shfl_xor(sq, off, 64);
    }
    __shared__ float rs[8], rq[8];
    const int lane = t & 63, wv = t >> 6;
    if (lane == 0) { rs[wv] = sum; rq[wv] = sq; }
    __syncthreads();
    float ts = 0.f, tq = 0.f;
    #pragma unroll
    for (int w = 0; w < 8; ++w) { ts += rs[w]; tq += rq[w]; }
    const float invD = 1.f / (float)NHW;
    float mean = ts * invD;
    float var  = tq * invD - mean * mean;
    float scal = rsqrtf(var + 1e-5f) * gamma[c];
    float shft = beta[c] - mean * scal;
    cnt = 0;
    for (int i = t; i < NHW; i += 512) {
        int n = i / HWSZ;
        int hw = i - n * HWSZ;
        int idx = (n * CC + c) * HWSZ + hw;
        out[idx] = vals[cnt++] * scal + shft;
    }
}

extern "C" void kernel_launch(void* const* d_in, const int* in_sizes, int n_in,
                              void* d_out, int out_size, void* d_ws, size_t ws_size,
                              hipStream_t stream) {
    const float* x     = (const float*)d_in[0];
    const float* cw    = (const float*)d_in[1];
    const float* cb    = (const float*)d_in[2];
    const float* gamma = (const float*)d_in[3];
    const float* beta  = (const float*)d_in[4];
    float* out = (float*)d_out;

    // d_out doubles as the fp32 accumulator for the partial sums over o.
    hipMemsetAsync(out, 0, (size_t)NN * CC * HWSZ * sizeof(float), stream);
    fuse_k1<<<dim3(MSZ, NN), 256, 0, stream>>>(x, cw, cb, out);
    fuse_k2<<<CC, 512, 0, stream>>>(out, x, gamma, beta);
}

// Round 3
// 94.427 us; speedup vs baseline: 1.5244x; 1.1244x over previous
//
#include <hip/hip_runtime.h>
#include <hip/hip_bf16.h>

// Problem constants
#define NN    32
#define CC    49
#define HWSZ  81
#define MSZ   24
#define KSZ   7
#define PADSZ 3
#define NHW   (NN*HWSZ)     // 2592
#define NCHW  (NN*CC*HWSZ)  // 127008

// LDS strides (in shorts / bf16 elements). All row strides * 2B are multiples
// of 16B (b128-aligned fragment loads) and chosen to stagger bank starts.
// Total LDS = 13312 + 13312 + 13824 + 9216 = 49664 B < 52 KB -> 3 blocks/CU.
#define XSB_S  104   // xsb[64][104]  : x[n] as bf16, rows c (0..48 data, 49..63 zero)
#define MSK_S  104   // msk[64][104]  : mask rows dd, cols hw (81..95 zero, rows 49..63 zero)
#define MSKT_S 72    // mskT[96][72]  : mask transposed, rows hw, cols dd
#define G_S    72    // gm[64][72]    : leaky(fk)[c][dd]

typedef __attribute__((ext_vector_type(8))) short short8;
typedef __attribute__((ext_vector_type(4))) short short4v;
typedef __attribute__((ext_vector_type(4))) float f32x4;

__device__ __forceinline__ short f2b(float v) {
    unsigned u = __float_as_uint(v);
    u += 0x7fffu + ((u >> 16) & 1u);      // round-to-nearest-even to bf16
    return (short)(u >> 16);
}

// Kernel 1: one block (256 thr = 4 waves) per (n, o).
//   phase 1: conv(K=7 over channel) + softmax(81) from global fp32 x -> msk/mskT (bf16 LDS)
//   phase 2: MFMA  fkT[dd][c] = msk(64x96) . xsb^T  -> leaky -> gm[c][dd] (bf16 LDS)
//   phase 3: MFMA  out_partial[c][hw] = gm(64x64) . mskT^T(64x96)
//            use_ws=1: plain stores to ws[(o*NN+n)][c][hw] (no contention)
//            use_ws=0: fp32 atomicAdd into acc (fallback)
__global__ __launch_bounds__(256) void fuse_k1(
    const float* __restrict__ x, const float* __restrict__ cw,
    const float* __restrict__ cb, float* __restrict__ acc, int use_ws)
{
    __shared__ short xsb [64 * XSB_S];    // 13312 B
    __shared__ short msk [64 * MSK_S];    // 13312 B
    __shared__ short mskT[96 * MSKT_S];   // 13824 B
    __shared__ short gm  [64 * G_S];      //  9216 B  (fully overwritten, no zeroing)

    const int o = blockIdx.x;          // 0..23
    const int n = blockIdx.y;          // 0..31
    const int t = threadIdx.x;
    const int lane = t & 63;
    const int wv = t >> 6;             // 0..3
    const int lr = lane & 15;          // MFMA row/col index
    const int lq = lane >> 4;          // MFMA k-group / reg-group

    // ---- zero-fill the padded LDS operands (16B per store)
    {
        f32x4 z = {0.f, 0.f, 0.f, 0.f};
        for (int i = t; i < 832; i += 256) {        // 6656 shorts each
            ((f32x4*)xsb)[i] = z;
            ((f32x4*)msk)[i] = z;
        }
        for (int i = t; i < 864; i += 256)          // 6912 shorts
            ((f32x4*)mskT)[i] = z;
    }

    const float* xg = x + (size_t)n * CC * HWSZ;
    float wk[KSZ];
    #pragma unroll
    for (int k = 0; k < KSZ; ++k) wk[k] = cw[o * KSZ + k];
    const float bias = cb[o];
    __syncthreads();

    // ---- stage x[n] into xsb (bf16, row-major [c][hw])
    for (int i = t; i < CC * HWSZ; i += 256) {
        int c = i / HWSZ, hw = i - c * HWSZ;
        xsb[c * XSB_S + hw] = f2b(xg[i]);
    }

    // ---- conv over channel dim + softmax over 81 cols; one dd-row per wave-iter.
    // Reads fp32 x from global (L1-resident) to keep softmax full precision.
    for (int dd = wv; dd < CC; dd += 4) {
        const int c0 = lane, c1 = lane + 64;
        float a0 = 0.f, a1 = 0.f;
        #pragma unroll
        for (int k = 0; k < KSZ; ++k) {
            int r = dd + k - PADSZ;
            if (r >= 0 && r < CC) {
                a0 += wk[k] * xg[r * HWSZ + c0];
                if (c1 < HWSZ) a1 += wk[k] * xg[r * HWSZ + c1];
            }
        }
        float m0 = bias + a0;
        float m1 = (c1 < HWSZ) ? bias + a1 : -1e30f;
        float mx = fmaxf(m0, m1);
        #pragma unroll
        for (int off = 32; off; off >>= 1) mx = fmaxf(mx, __shfl_xor(mx, off, 64));
        float e0 = __expf(m0 - mx);
        float e1 = (c1 < HWSZ) ? __expf(m1 - mx) : 0.f;
        float sm = e0 + e1;
        #pragma unroll
        for (int off = 32; off; off >>= 1) sm += __shfl_xor(sm, off, 64);
        float inv = 1.f / sm;
        short b0 = f2b(e0 * inv);
        msk [dd * MSK_S  + c0] = b0;
        mskT[c0 * MSKT_S + dd] = b0;
        if (c1 < HWSZ) {
            short b1 = f2b(e1 * inv);
            msk [dd * MSK_S  + c1] = b1;
            mskT[c1 * MSKT_S + dd] = b1;
        }
    }
    __syncthreads();

    // ---- matmul-2 (MFMA): fkT[dd][c] = sum_hw msk[dd][hw] * xsb[c][hw]
    // M=dd (4 tiles, one per wave), N=c (4 tiles), K=hw (96, 3 steps).
    {
        short8 a2[3];
        #pragma unroll
        for (int ks = 0; ks < 3; ++ks)
            a2[ks] = *(const short8*)&msk[(wv * 16 + lr) * MSK_S + ks * 32 + lq * 8];
        #pragma unroll
        for (int nt = 0; nt < 4; ++nt) {
            f32x4 accv = {0.f, 0.f, 0.f, 0.f};
            #pragma unroll
            for (int ks = 0; ks < 3; ++ks) {
                short8 b = *(const short8*)&xsb[(nt * 16 + lr) * XSB_S + ks * 32 + lq * 8];
                accv = __builtin_amdgcn_mfma_f32_16x16x32_bf16(a2[ks], b, accv, 0, 0, 0);
            }
            // C-layout: lane holds fkT[dd = wv*16 + lq*4 + r][c = nt*16 + lr]
            // leaky, then store transposed into gm[c][dd] (4 consecutive dd -> b64)
            short4v pk;
            #pragma unroll
            for (int r = 0; r < 4; ++r) {
                float v = accv[r];
                v = (v >= 0.f) ? v : 0.01f * v;
                pk[r] = f2b(v);
            }
            *(short4v*)&gm[(nt * 16 + lr) * G_S + wv * 16 + lq * 4] = pk;
        }
    }
    __syncthreads();

    // ---- matmul-1 (MFMA): out_partial[c][hw] = sum_dd gm[c][dd] * mskT[hw][dd]
    // M=c (4 tiles, one per wave), N=hw (6 tiles), K=dd (64, 2 steps).
    {
        float* dstn = use_ws ? (acc + (size_t)(o * NN + n) * CC * HWSZ)
                             : (acc + (size_t)n * CC * HWSZ);
        short8 a1[2];
        #pragma unroll
        for (int ks = 0; ks < 2; ++ks)
            a1[ks] = *(const short8*)&gm[(wv * 16 + lr) * G_S + ks * 32 + lq * 8];
        #pragma unroll
        for (int nt = 0; nt < 6; ++nt) {
            f32x4 accv = {0.f, 0.f, 0.f, 0.f};
            #pragma unroll
            for (int ks = 0; ks < 2; ++ks) {
                short8 b = *(const short8*)&mskT[(nt * 16 + lr) * MSKT_S + ks * 32 + lq * 8];
                accv = __builtin_amdgcn_mfma_f32_16x16x32_bf16(a1[ks], b, accv, 0, 0, 0);
            }
            // C-layout: lane holds out[c = wv*16 + lq*4 + r][hw = nt*16 + lr]
            int hw = nt * 16 + lr;
            if (hw < HWSZ) {
                int cb = wv * 16 + lq * 4;
                if (use_ws) {
                    #pragma unroll
                    for (int r = 0; r < 4; ++r) {
                        int c = cb + r;
                        if (c < CC) dstn[c * HWSZ + hw] = accv[r];
                    }
                } else {
                    #pragma unroll
                    for (int r = 0; r < 4; ++r) {
                        int c = cb + r;
                        if (c < CC) atomicAdd(dstn + c * HWSZ + hw, accv[r]);
                    }
                }
            }
        }
    }
}

// Kernel 2 (ws path): one block per channel c (512 thr). Sums the 24 per-o
// partials, adds residual, batch-norm over (N,H,W), writes d_out.
__global__ __launch_bounds__(512) void fuse_k2w(
    const float* __restrict__ ws, const float* __restrict__ x,
    const float* __restrict__ gamma, const float* __restrict__ beta,
    float* __restrict__ out)
{
    const int c = blockIdx.x;
    const int t = threadIdx.x;
    float vals[6];
    float sum = 0.f, sq = 0.f;
    int cnt = 0;
    for (int i = t; i < NHW; i += 512) {
        int n = i / HWSZ;
        int hw = i - n * HWSZ;
        int idx = (n * CC + c) * HWSZ + hw;
        const float* p = ws + idx;
        float v = x[idx];
        #pragma unroll
        for (int o = 0; o < MSZ; ++o) v += p[(size_t)o * NCHW];
        vals[cnt++] = v;
        sum += v; sq += v * v;
    }
    #pragma unroll
    for (int off = 32; off; off >>= 1) {
        sum += __shfl_xor(sum, off, 64);
        sq  += __shfl_xor(sq, off, 64);
    }
    __shared__ float rs[8], rq[8];
    const int lane = t & 63, wv = t >> 6;
    if (lane == 0) { rs[wv] = sum; rq[wv] = sq; }
    __syncthreads();
    float ts = 0.f, tq = 0.f;
    #pragma unroll
    for (int w = 0; w < 8; ++w) { ts += rs[w]; tq += rq[w]; }
    const float invD = 1.f / (float)NHW;
    float mean = ts * invD;
    float var  = tq * invD - mean * mean;
    float scal = rsqrtf(var + 1e-5f) * gamma[c];
    float shft = beta[c] - mean * scal;
    cnt = 0;
    for (int i = t; i < NHW; i += 512) {
        int n = i / HWSZ;
        int hw = i - n * HWSZ;
        out[(n * CC + c) * HWSZ + hw] = vals[cnt++] * scal + shft;
    }
}

// Kernel 2 (fallback, atomic path): residual add + batch-norm in-place on d_out.
__global__ __launch_bounds__(512) void fuse_k2(
    float* __restrict__ out, const float* __restrict__ x,
    const float* __restrict__ gamma, const float* __restrict__ beta)
{
    const int c = blockIdx.x;
    const int t = threadIdx.x;
    float vals[6];
    float sum = 0.f, sq = 0.f;
    int cnt = 0;
    for (int i = t; i < NHW; i += 512) {
        int n = i / HWSZ;
        int hw = i - n * HWSZ;
        int idx = (n * CC + c) * HWSZ + hw;
        float v = out[idx] + x[idx];
        vals[cnt++] = v;
        sum += v; sq += v * v;
    }
    #pragma unroll
    for (int off = 32; off; off >>= 1) {
        sum += __shfl_xor(sum, off, 64);
        sq  += __shfl_xor(sq, off, 64);
    }
    __shared__ float rs[8], rq[8];
    const int lane = t & 63, wv = t >> 6;
    if (lane == 0) { rs[wv] = sum; rq[wv] = sq; }
    __syncthreads();
    float ts = 0.f, tq = 0.f;
    #pragma unroll
    for (int w = 0; w < 8; ++w) { ts += rs[w]; tq += rq[w]; }
    const float invD = 1.f / (float)NHW;
    float mean = ts * invD;
    float var  = tq * invD - mean * mean;
    float scal = rsqrtf(var + 1e-5f) * gamma[c];
    float shft = beta[c] - mean * scal;
    cnt = 0;
    for (int i = t; i < NHW; i += 512) {
        int n = i / HWSZ;
        int hw = i - n * HWSZ;
        out[(n * CC + c) * HWSZ + hw] = vals[cnt++] * scal + shft;
    }
}

extern "C" void kernel_launch(void* const* d_in, const int* in_sizes, int n_in,
                              void* d_out, int out_size, void* d_ws, size_t ws_size,
                              hipStream_t stream) {
    const float* x     = (const float*)d_in[0];
    const float* cw    = (const float*)d_in[1];
    const float* cb    = (const float*)d_in[2];
    const float* gamma = (const float*)d_in[3];
    const float* beta  = (const float*)d_in[4];
    float* out = (float*)d_out;

    const size_t need = (size_t)MSZ * NCHW * sizeof(float);   // 12.19 MB
    if (ws_size >= need) {
        float* ws = (float*)d_ws;
        fuse_k1<<<dim3(MSZ, NN), 256, 0, stream>>>(x, cw, cb, ws, 1);
        fuse_k2w<<<CC, 512, 0, stream>>>(ws, x, gamma, beta, out);
    } else {
        hipMemsetAsync(out, 0, (size_t)NCHW * sizeof(float), stream);
        fuse_k1<<<dim3(MSZ, NN), 256, 0, stream>>>(x, cw, cb, out, 0);
        fuse_k2<<<CC, 512, 0, stream>>>(out, x, gamma, beta);
    }
}

// Round 5
// 85.035 us; speedup vs baseline: 1.6927x; 1.1104x over previous
//
#include <hip/hip_runtime.h>
#include <hip/hip_bf16.h>

// Problem constants
#define NN    32
#define CC    49
#define HWSZ  81
#define MSZ   24
#define KSZ   7
#define PADSZ 3
#define NHW   (NN*HWSZ)     // 2592
#define NCHW  (NN*CC*HWSZ)  // 127008

// LDS strides (in shorts / bf16 elements). All row strides * 2B are multiples
// of 16B (b128-aligned fragment loads) and chosen to stagger bank starts.
// Total LDS = 13312 + 13312 + 13824 + 9216 = 49664 B < 52 KB -> 3 blocks/CU.
#define XSB_S  104   // xsb[64][104]  : x[n] as bf16 (FULLY zero-filled: pad NaN-safe)
#define MSK_S  104   // msk[64][104]  : mask rows dd (FULLY zero-filled)
#define MSKT_S 72    // mskT[96][72]  : mask transposed (FULLY zero-filled)
#define G_S    72    // gm[64][72]    : leaky(fk)[c][dd] (fully overwritten - no fill)

typedef __attribute__((ext_vector_type(8))) short short8;
typedef __attribute__((ext_vector_type(4))) short short4v;
typedef __attribute__((ext_vector_type(4))) float f32x4;

__device__ __forceinline__ short f2b(float v) {
    unsigned u = __float_as_uint(v);
    u += 0x7fffu + ((u >> 16) & 1u);      // round-to-nearest-even to bf16
    return (short)(u >> 16);
}

// Kernel 1: one block (256 thr = 4 waves) per (n, o).
//   phase 0: zero-fill xsb/msk/mskT pads; BARRIER (overlaps softmax's msk writes)
//   phase 1: stage x->xsb(bf16); conv(K=7 over channel)+softmax(81), 4 rows/wave,
//            16-lane shuffle reductions (4 steps), fp32 reads from global (L1-hot)
//   phase 2: MFMA  fkT[dd][c] = msk(64x96) . xsb^T -> leaky -> gm[c][dd]
//   phase 3: MFMA  out_partial[c][hw] = gm(64x64) . mskT^T -> stores to ws
// NaN-safety: every LDS word an MFMA reads is either real data or explicit 0.
// (0 * uninitialized-NaN = NaN, so pads MUST be zeroed, not argued away.)
__global__ __launch_bounds__(256) void fuse_k1(
    const float* __restrict__ x, const float* __restrict__ cw,
    const float* __restrict__ cb, float* __restrict__ acc, int use_ws)
{
    __shared__ short xsb [64 * XSB_S];    // 13312 B
    __shared__ short msk [64 * MSK_S];    // 13312 B
    __shared__ short mskT[96 * MSKT_S];   // 13824 B
    __shared__ short gm  [64 * G_S];      //  9216 B

    const int o = blockIdx.x;          // 0..23
    const int n = blockIdx.y;          // 0..31
    const int t = threadIdx.x;
    const int lane = t & 63;
    const int wv = t >> 6;             // 0..3
    const int lr = lane & 15;
    const int lq = lane >> 4;          // quad index 0..3

    // ---- phase 0: zero-fill all MFMA-read LDS (16B per store)
    {
        f32x4 z = {0.f, 0.f, 0.f, 0.f};
        for (int i = t; i < 832; i += 256) {        // 6656 shorts each
            ((f32x4*)xsb)[i] = z;
            ((f32x4*)msk)[i] = z;
        }
        for (int i = t; i < 864; i += 256)          // 6912 shorts
            ((f32x4*)mskT)[i] = z;
    }

    const float* xg = x + (size_t)n * CC * HWSZ;
    float wk[KSZ];
    #pragma unroll
    for (int k = 0; k < KSZ; ++k) wk[k] = cw[o * KSZ + k];
    const float bias = cb[o];
    __syncthreads();   // zero-fill must complete before softmax/staging writes

    // ---- stage x[n] into xsb (bf16, row-major [c][hw])
    for (int i = t; i < CC * HWSZ; i += 256) {
        int c = i / HWSZ, hw = i - c * HWSZ;
        xsb[c * XSB_S + hw] = f2b(xg[i]);
    }

    // ---- conv + softmax: 16 rows per block-iteration (4 per wave, row = lq).
    // Lane lr covers cols lr, lr+16, lr+32, lr+48, lr+64 (+80 on lr==0).
    #pragma unroll
    for (int it = 0; it < 4; ++it) {
        int dd = it * 16 + wv * 4 + lq;
        if (dd < CC) {
            float a0 = 0.f, a1 = 0.f, a2 = 0.f, a3 = 0.f, a4 = 0.f, a5 = 0.f;
            #pragma unroll
            for (int k = 0; k < KSZ; ++k) {
                int r = dd + k - PADSZ;
                if (r >= 0 && r < CC) {
                    const float* xr = xg + r * HWSZ;
                    float w = wk[k];
                    a0 += w * xr[lr];
                    a1 += w * xr[lr + 16];
                    a2 += w * xr[lr + 32];
                    a3 += w * xr[lr + 48];
                    a4 += w * xr[lr + 64];
                    if (lr == 0) a5 += w * xr[80];
                }
            }
            a0 += bias; a1 += bias; a2 += bias; a3 += bias; a4 += bias;
            a5 = (lr == 0) ? (a5 + bias) : -1e30f;
            float mx = fmaxf(fmaxf(fmaxf(a0, a1), fmaxf(a2, a3)), fmaxf(a4, a5));
            #pragma unroll
            for (int off = 8; off; off >>= 1) mx = fmaxf(mx, __shfl_xor(mx, off, 64));
            float e0 = __expf(a0 - mx), e1 = __expf(a1 - mx), e2 = __expf(a2 - mx);
            float e3 = __expf(a3 - mx), e4 = __expf(a4 - mx);
            float e5 = (lr == 0) ? __expf(a5 - mx) : 0.f;
            float s = e0 + e1 + e2 + e3 + e4 + e5;
            #pragma unroll
            for (int off = 8; off; off >>= 1) s += __shfl_xor(s, off, 64);
            float inv = 1.f / s;
            short b0 = f2b(e0 * inv), b1 = f2b(e1 * inv), b2 = f2b(e2 * inv);
            short b3 = f2b(e3 * inv), b4 = f2b(e4 * inv);
            short* mrow = msk + dd * MSK_S;
            mrow[lr]      = b0;  mskT[(lr     ) * MSKT_S + dd] = b0;
            mrow[lr + 16] = b1;  mskT[(lr + 16) * MSKT_S + dd] = b1;
            mrow[lr + 32] = b2;  mskT[(lr + 32) * MSKT_S + dd] = b2;
            mrow[lr + 48] = b3;  mskT[(lr + 48) * MSKT_S + dd] = b3;
            mrow[lr + 64] = b4;  mskT[(lr + 64) * MSKT_S + dd] = b4;
            if (lr == 0) {
                short b5 = f2b(e5 * inv);
                mrow[80] = b5;   mskT[80 * MSKT_S + dd] = b5;
            }
        }
    }
    __syncthreads();

    // ---- matmul-2 (MFMA): fkT[dd][c] = sum_hw msk[dd][hw] * xsb[c][hw]
    // M=dd (4 tiles, one per wave), N=c (4 tiles), K=hw (96, 3 steps).
    {
        short8 a2[3];
        #pragma unroll
        for (int ks = 0; ks < 3; ++ks)
            a2[ks] = *(const short8*)&msk[(wv * 16 + lr) * MSK_S + ks * 32 + lq * 8];
        #pragma unroll
        for (int nt = 0; nt < 4; ++nt) {
            f32x4 accv = {0.f, 0.f, 0.f, 0.f};
            #pragma unroll
            for (int ks = 0; ks < 3; ++ks) {
                short8 b = *(const short8*)&xsb[(nt * 16 + lr) * XSB_S + ks * 32 + lq * 8];
                accv = __builtin_amdgcn_mfma_f32_16x16x32_bf16(a2[ks], b, accv, 0, 0, 0);
            }
            // C-layout: lane holds fkT[dd = wv*16 + lq*4 + r][c = nt*16 + lr]
            short4v pk;
            #pragma unroll
            for (int r = 0; r < 4; ++r) {
                float v = accv[r];
                v = (v >= 0.f) ? v : 0.01f * v;
                pk[r] = f2b(v);
            }
            *(short4v*)&gm[(nt * 16 + lr) * G_S + wv * 16 + lq * 4] = pk;
        }
    }
    __syncthreads();

    // ---- matmul-1 (MFMA): out_partial[c][hw] = sum_dd gm[c][dd] * mskT[hw][dd]
    // M=c (4 tiles, one per wave), N=hw (6 tiles), K=dd (64, 2 steps).
    {
        float* dstn = use_ws ? (acc + (size_t)(o * NN + n) * CC * HWSZ)
                             : (acc + (size_t)n * CC * HWSZ);
        short8 a1[2];
        #pragma unroll
        for (int ks = 0; ks < 2; ++ks)
            a1[ks] = *(const short8*)&gm[(wv * 16 + lr) * G_S + ks * 32 + lq * 8];
        #pragma unroll
        for (int nt = 0; nt < 6; ++nt) {
            f32x4 accv = {0.f, 0.f, 0.f, 0.f};
            #pragma unroll
            for (int ks = 0; ks < 2; ++ks) {
                short8 b = *(const short8*)&mskT[(nt * 16 + lr) * MSKT_S + ks * 32 + lq * 8];
                accv = __builtin_amdgcn_mfma_f32_16x16x32_bf16(a1[ks], b, accv, 0, 0, 0);
            }
            int hw = nt * 16 + lr;
            if (hw < HWSZ) {
                int cb = wv * 16 + lq * 4;
                if (use_ws) {
                    #pragma unroll
                    for (int r = 0; r < 4; ++r) {
                        int c = cb + r;
                        if (c < CC) dstn[c * HWSZ + hw] = accv[r];
                    }
                } else {
                    #pragma unroll
                    for (int r = 0; r < 4; ++r) {
                        int c = cb + r;
                        if (c < CC) atomicAdd(dstn + c * HWSZ + hw, accv[r]);
                    }
                }
            }
        }
    }
}

// Kernel 2 (ws path): one block per channel c (1024 thr). Sums the 24 per-o
// partials, adds residual, batch-norm over (N,H,W), writes d_out.
__global__ __launch_bounds__(1024) void fuse_k2w(
    const float* __restrict__ ws, const float* __restrict__ x,
    const float* __restrict__ gamma, const float* __restrict__ beta,
    float* __restrict__ out)
{
    const int c = blockIdx.x;
    const int t = threadIdx.x;
    float vals[3];
    float sum = 0.f, sq = 0.f;
    int cnt = 0;
    for (int i = t; i < NHW; i += 1024) {
        int n = i / HWSZ;
        int hw = i - n * HWSZ;
        int idx = (n * CC + c) * HWSZ + hw;
        const float* p = ws + idx;
        float v = x[idx];
        #pragma unroll
        for (int o = 0; o < MSZ; ++o) v += p[(size_t)o * NCHW];
        vals[cnt++] = v;
        sum += v; sq += v * v;
    }
    #pragma unroll
    for (int off = 32; off; off >>= 1) {
        sum += __shfl_xor(sum, off, 64);
        sq  += __shfl_xor(sq, off, 64);
    }
    __shared__ float rs[16], rq[16];
    const int lane = t & 63, wv = t >> 6;
    if (lane == 0) { rs[wv] = sum; rq[wv] = sq; }
    __syncthreads();
    float ts = 0.f, tq = 0.f;
    #pragma unroll
    for (int w = 0; w < 16; ++w) { ts += rs[w]; tq += rq[w]; }
    const float invD = 1.f / (float)NHW;
    float mean = ts * invD;
    float var  = tq * invD - mean * mean;
    float scal = rsqrtf(var + 1e-5f) * gamma[c];
    float shft = beta[c] - mean * scal;
    cnt = 0;
    for (int i = t; i < NHW; i += 1024) {
        int n = i / HWSZ;
        int hw = i - n * HWSZ;
        out[(n * CC + c) * HWSZ + hw] = vals[cnt++] * scal + shft;
    }
}

// Kernel 2 (fallback, atomic path): residual add + batch-norm in-place on d_out.
__global__ __launch_bounds__(1024) void fuse_k2(
    float* __restrict__ out, const float* __restrict__ x,
    const float* __restrict__ gamma, const float* __restrict__ beta)
{
    const int c = blockIdx.x;
    const int t = threadIdx.x;
    float vals[3];
    float sum = 0.f, sq = 0.f;
    int cnt = 0;
    for (int i = t; i < NHW; i += 1024) {
        int n = i / HWSZ;
        int hw = i - n * HWSZ;
        int idx = (n * CC + c) * HWSZ + hw;
        float v = out[idx] + x[idx];
        vals[cnt++] = v;
        sum += v; sq += v * v;
    }
    #pragma unroll
    for (int off = 32; off; off >>= 1) {
        sum += __shfl_xor(sum, off, 64);
        sq  += __shfl_xor(sq, off, 64);
    }
    __shared__ float rs[16], rq[16];
    const int lane = t & 63, wv = t >> 6;
    if (lane == 0) { rs[wv] = sum; rq[wv] = sq; }
    __syncthreads();
    float ts = 0.f, tq = 0.f;
    #pragma unroll
    for (int w = 0; w < 16; ++w) { ts += rs[w]; tq += rq[w]; }
    const float invD = 1.f / (float)NHW;
    float mean = ts * invD;
    float var  = tq * invD - mean * mean;
    float scal = rsqrtf(var + 1e-5f) * gamma[c];
    float shft = beta[c] - mean * scal;
    cnt = 0;
    for (int i = t; i < NHW; i += 1024) {
        int n = i / HWSZ;
        int hw = i - n * HWSZ;
        out[(n * CC + c) * HWSZ + hw] = vals[cnt++] * scal + shft;
    }
}

extern "C" void kernel_launch(void* const* d_in, const int* in_sizes, int n_in,
                              void* d_out, int out_size, void* d_ws, size_t ws_size,
                              hipStream_t stream) {
    const float* x     = (const float*)d_in[0];
    const float* cw    = (const float*)d_in[1];
    const float* cb    = (const float*)d_in[2];
    const float* gamma = (const float*)d_in[3];
    const float* beta  = (const float*)d_in[4];
    float* out = (float*)d_out;

    const size_t need = (size_t)MSZ * NCHW * sizeof(float);   // 12.19 MB
    if (ws_size >= need) {
        float* ws = (float*)d_ws;
        fuse_k1<<<dim3(MSZ, NN), 256, 0, stream>>>(x, cw, cb, ws, 1);
        fuse_k2w<<<CC, 1024, 0, stream>>>(ws, x, gamma, beta, out);
    } else {
        hipMemsetAsync(out, 0, (size_t)NCHW * sizeof(float), stream);
        fuse_k1<<<dim3(MSZ, NN), 256, 0, stream>>>(x, cw, cb, out, 0);
        fuse_k2<<<CC, 1024, 0, stream>>>(out, x, gamma, beta);
    }
}